// Round 5
// baseline (337.076 us; speedup 1.0000x reference)
//
#include <hip/hip_runtime.h>
#include <math.h>

// Problem constants (fixed by setup_inputs)
#define B_    8
#define T_    8192
#define LIN   1536
#define D_    768
#define H_    8
#define E_    96
#define TT    32            // tokens per block in fallback fused k1
#define NCH   64            // token chunks per batch in kernel 3
#define CHT   (T_ / NCH)    // 128 tokens per chunk
#define TPW3  (CHT / 4)     // 32 tokens per wave in kernel 3
#define NWA   4096          // total waves in kA (1024 blocks x 4 waves)

typedef float f32x4 __attribute__((ext_vector_type(4)));
typedef short s16x8 __attribute__((ext_vector_type(8)));
typedef short s16x4 __attribute__((ext_vector_type(4)));

static __device__ __forceinline__ float resize_w(int j, int* i0) {
    const float SCALE = (float)(1535.0 / 767.0);   // (L_IN-1)/(D-1), f32 like jnp
    float pos = (float)j * SCALE;
    int a = (int)floorf(pos);
    if (a > LIN - 1) a = LIN - 1;
    *i0 = a;
    return pos - (float)a;
}

static __device__ __forceinline__ float fast_sigmoid(float v) {
    return 1.0f / (1.0f + __expf(-v));
}
static __device__ __forceinline__ float fast_tanh(float v) {
    float t = __expf(-2.0f * v);
    return (1.0f - t) / (1.0f + t);
}
static __device__ __forceinline__ short f2bf(float f) {   // RNE f32 -> bf16 bits
    unsigned u = __float_as_uint(f);
    unsigned r = (u + 0x7FFFu + ((u >> 16) & 1u)) >> 16;
    return (short)r;
}

// ---------------------------------------------------------------------------
// Kernel 0: weight prep. Wa,Wb [h][e][f] f32 -> wtA,wtB [h][f][e] bf16.
// ---------------------------------------------------------------------------
__global__ __launch_bounds__(256)
void k0_wprep(const float* __restrict__ Wa, const float* __restrict__ Wb,
              short* __restrict__ wtA, short* __restrict__ wtB)
{
    int o = blockIdx.x * 256 + threadIdx.x;
    if (o >= H_ * E_ * E_) return;
    int e = o % E_;
    int f = (o / E_) % E_;
    int h = o / (E_ * E_);
    int in = h * E_ * E_ + e * E_ + f;
    wtA[o] = f2bf(Wa[in]);
    wtB[o] = f2bf(Wb[in]);
}

// ---------------------------------------------------------------------------
// Kernel A (split path): resize + LayerNorm, one wave per token, grid-stride.
// Zero LDS, zero barriers. Lane owns head h = lane>>3, e-range e0 = (lane&7)*12
// (orig features j = (e0+k)*8 + h) so the 12 bf16 outputs land contiguously at
// xnb[tok][lane*12 .. +12] ([tok][h][e] head-major layout for kB's A-frags).
// ---------------------------------------------------------------------------
__global__ __launch_bounds__(256)
void kA_resln(const float* __restrict__ x,
              const float* __restrict__ gamma, const float* __restrict__ beta,
              short* __restrict__ xnb)
{
    const int tid  = threadIdx.x;
    const int lane = tid & 63;
    const int wv   = tid >> 6;
    const int gw   = blockIdx.x * 4 + wv;   // 0..NWA-1

    const int h  = lane >> 3;
    const int e0 = (lane & 7) * 12;

    float gm[12], btv[12], wl[12];
    int   i0[12];
    #pragma unroll
    for (int k = 0; k < 12; ++k) {
        int j = (e0 + k) * 8 + h;
        gm[k]  = gamma[j];
        btv[k] = beta[j];
        wl[k]  = resize_w(j, &i0[k]);
    }

    for (int t = gw; t < B_ * T_; t += NWA) {
        const float* xrow = x + (size_t)t * LIN;
        float xr[12];
        float sum = 0.0f, ssq = 0.0f;
        #pragma unroll
        for (int k = 0; k < 12; ++k) {
            int a  = i0[k];
            int b2 = (a + 1 < LIN) ? a + 1 : LIN - 1;
            float v = xrow[a] * (1.0f - wl[k]) + xrow[b2] * wl[k];
            xr[k] = v; sum += v; ssq += v * v;
        }
        #pragma unroll
        for (int o = 1; o < 64; o <<= 1) {
            sum += __shfl_xor(sum, o, 64);
            ssq += __shfl_xor(ssq, o, 64);
        }
        float mu = sum * (1.0f / D_);
        float rs = 1.0f / sqrtf(ssq * (1.0f / D_) - mu * mu + 1e-5f);

        s16x4 p0, p1, p2;
        #pragma unroll
        for (int k = 0; k < 4; ++k) p0[k] = f2bf((xr[k]     - mu) * rs * gm[k]     + btv[k]);
        #pragma unroll
        for (int k = 0; k < 4; ++k) p1[k] = f2bf((xr[k + 4] - mu) * rs * gm[k + 4] + btv[k + 4]);
        #pragma unroll
        for (int k = 0; k < 4; ++k) p2[k] = f2bf((xr[k + 8] - mu) * rs * gm[k + 8] + btv[k + 8]);

        short* dst = xnb + (size_t)t * D_ + lane * 12;   // 24B per lane, 8B aligned
        *(s16x4*)(dst)     = p0;
        *(s16x4*)(dst + 4) = p1;
        *(s16x4*)(dst + 8) = p2;
    }
}

// ---------------------------------------------------------------------------
// Kernel B (split path): MFMA scoring from global bf16 xn. No LDS, no barrier.
// Wave = 32 tokens (2 M-tiles) x all 8 heads; block = 4 waves = 128 tokens.
// ---------------------------------------------------------------------------
__global__ __launch_bounds__(256)
void kB_score(const short* __restrict__ xnb,
              const short* __restrict__ wtA, const short* __restrict__ wtB,
              const float* __restrict__ ba, const float* __restrict__ bb,
              const float* __restrict__ Wc, const float* __restrict__ bc,
              float* __restrict__ s_out)
{
    const int tid  = threadIdx.x;
    const int lane = tid & 63;
    const int wv   = tid >> 6;
    const int ln15 = lane & 15;
    const int q    = lane >> 4;
    const int t0w  = (blockIdx.x * 4 + wv) * 32;

    float hacc[2][4];
    #pragma unroll
    for (int mt = 0; mt < 2; ++mt)
        #pragma unroll
        for (int r = 0; r < 4; ++r) hacc[mt][r] = 0.0f;

    #pragma unroll
    for (int h = 0; h < H_; ++h) {
        // A fragments: row = token, k = kk*32 + q*8 + i  (16B contiguous loads)
        s16x8 afr[2][3];
        #pragma unroll
        for (int mt = 0; mt < 2; ++mt)
            #pragma unroll
            for (int kk = 0; kk < 3; ++kk)
                afr[mt][kk] = *(const s16x8*)&xnb[(size_t)(t0w + mt * 16 + ln15) * D_
                                                 + h * E_ + kk * 32 + q * 8];

        f32x4 accA[2][6], accG[2][6];
        #pragma unroll
        for (int mt = 0; mt < 2; ++mt)
            #pragma unroll
            for (int nt = 0; nt < 6; ++nt) {
                accA[mt][nt] = (f32x4){0.f, 0.f, 0.f, 0.f};
                accG[mt][nt] = (f32x4){0.f, 0.f, 0.f, 0.f};
            }

        #pragma unroll
        for (int nt = 0; nt < 6; ++nt) {
            const short* rA = wtA + h * (E_ * E_) + (nt * 16 + ln15) * E_ + q * 8;
            const short* rB = wtB + h * (E_ * E_) + (nt * 16 + ln15) * E_ + q * 8;
            #pragma unroll
            for (int kk = 0; kk < 3; ++kk) {
                s16x8 bA = *(const s16x8*)(rA + kk * 32);
                s16x8 bG = *(const s16x8*)(rB + kk * 32);
                #pragma unroll
                for (int mt = 0; mt < 2; ++mt) {
                    accA[mt][nt] = __builtin_amdgcn_mfma_f32_16x16x32_bf16(afr[mt][kk], bA, accA[mt][nt], 0, 0, 0);
                    accG[mt][nt] = __builtin_amdgcn_mfma_f32_16x16x32_bf16(afr[mt][kk], bG, accG[mt][nt], 0, 0, 0);
                }
            }
        }

        // Activations + Wc.  D mapping: col f = nt*16+ln15, row = q*4 + r.
        #pragma unroll
        for (int nt = 0; nt < 6; ++nt) {
            int f = nt * 16 + ln15;
            float bav = ba[h * E_ + f];
            float bbv = bb[h * E_ + f];
            float wcv = Wc[h * E_ + f];
            #pragma unroll
            for (int mt = 0; mt < 2; ++mt)
                #pragma unroll
                for (int r = 0; r < 4; ++r)
                    hacc[mt][r] += fast_tanh(accA[mt][nt][r] + bav)
                                 * fast_sigmoid(accG[mt][nt][r] + bbv) * wcv;
        }
    }

    // reduce over the 16 lanes holding the 96 f-columns
    #pragma unroll
    for (int mt = 0; mt < 2; ++mt)
        #pragma unroll
        for (int r = 0; r < 4; ++r) {
            float v = hacc[mt][r];
            v += __shfl_xor(v, 1, 64);
            v += __shfl_xor(v, 2, 64);
            v += __shfl_xor(v, 4, 64);
            v += __shfl_xor(v, 8, 64);
            hacc[mt][r] = v;
        }

    float bcsum = 0.0f;
    #pragma unroll
    for (int h2 = 0; h2 < H_; ++h2) bcsum += bc[h2];

    if (ln15 == 0) {
        #pragma unroll
        for (int mt = 0; mt < 2; ++mt)
            #pragma unroll
            for (int r = 0; r < 4; ++r)
                s_out[t0w + mt * 16 + q * 4 + r] = (hacc[mt][r] + bcsum) * (1.0f / H_);
    }
}

// ---------------------------------------------------------------------------
// Fallback fused kernel 1 (R4, proven): used when ws_size can't hold xnb.
// ---------------------------------------------------------------------------
__global__ __launch_bounds__(256)
void k1_score(const float* __restrict__ x,
              const float* __restrict__ gamma, const float* __restrict__ beta,
              const short* __restrict__ wtA, const short* __restrict__ wtB,
              const float* __restrict__ ba, const float* __restrict__ bb,
              const float* __restrict__ Wc, const float* __restrict__ bc,
              float* __restrict__ s_out)
{
    __shared__ __align__(16) short xnt[TT * D_];
    __shared__ float red2[TT][2];

    const int tid  = threadIdx.x;
    const int lane = tid & 63;
    const int wv   = tid >> 6;
    const int bt0  = blockIdx.x * TT;

    {
        float gm[12], btv[12], wl[12];
        int   i0[12];
        #pragma unroll
        for (int k = 0; k < 12; ++k) {
            int j = lane + k * 64;
            gm[k] = gamma[j];
            btv[k] = beta[j];
            wl[k] = resize_w(j, &i0[k]);
        }
        for (int tt = 0; tt < 8; ++tt) {
            const int tok = wv * 8 + tt;
            const float* xrow = x + (size_t)(bt0 + tok) * LIN;
            float xr[12];
            float sum = 0.0f, ssq = 0.0f;
            #pragma unroll
            for (int k = 0; k < 12; ++k) {
                int a = i0[k];
                int b2 = (a + 1 < LIN) ? a + 1 : LIN - 1;
                float v = xrow[a] * (1.0f - wl[k]) + xrow[b2] * wl[k];
                xr[k] = v; sum += v; ssq += v * v;
            }
            #pragma unroll
            for (int o = 1; o < 64; o <<= 1) {
                sum += __shfl_xor(sum, o, 64);
                ssq += __shfl_xor(ssq, o, 64);
            }
            float mu = sum * (1.0f / D_);
            float rs = 1.0f / sqrtf(ssq * (1.0f / D_) - mu * mu + 1e-5f);
            #pragma unroll
            for (int k = 0; k < 12; ++k) {
                int j = lane + k * 64;
                float xnv = (xr[k] - mu) * rs * gm[k] + btv[k];
                int sidx = (tok * D_ + (j & 7) * E_ + (j >> 3)) ^ ((tok & 7) << 3);
                xnt[sidx] = f2bf(xnv);
            }
        }
    }
    __syncthreads();

    const int mtile = wv & 1;
    const int hg    = wv >> 1;
    const int ln15  = lane & 15;
    const int q     = lane >> 4;
    const int tokA  = mtile * 16 + ln15;
    const int swzA  = (tokA & 7) << 3;

    float hacc[4] = {0.0f, 0.0f, 0.0f, 0.0f};

    #pragma unroll
    for (int hh = 0; hh < 4; ++hh) {
        const int h = hg * 4 + hh;
        s16x8 afr[3];
        #pragma unroll
        for (int kk = 0; kk < 3; ++kk) {
            int sidx = (tokA * D_ + h * E_ + kk * 32 + q * 8) ^ swzA;
            afr[kk] = *(const s16x8*)&xnt[sidx];
        }
        f32x4 accA[6], accG[6];
        #pragma unroll
        for (int nt = 0; nt < 6; ++nt) {
            accA[nt] = (f32x4){0.f, 0.f, 0.f, 0.f};
            accG[nt] = (f32x4){0.f, 0.f, 0.f, 0.f};
        }
        #pragma unroll
        for (int nt = 0; nt < 6; ++nt) {
            const short* rowA = wtA + h * (E_ * E_) + (nt * 16 + ln15) * E_ + q * 8;
            const short* rowB = wtB + h * (E_ * E_) + (nt * 16 + ln15) * E_ + q * 8;
            #pragma unroll
            for (int kk = 0; kk < 3; ++kk) {
                s16x8 bA = *(const s16x8*)(rowA + kk * 32);
                s16x8 bG = *(const s16x8*)(rowB + kk * 32);
                accA[nt] = __builtin_amdgcn_mfma_f32_16x16x32_bf16(afr[kk], bA, accA[nt], 0, 0, 0);
                accG[nt] = __builtin_amdgcn_mfma_f32_16x16x32_bf16(afr[kk], bG, accG[nt], 0, 0, 0);
            }
        }
        float v0 = 0.f, v1 = 0.f, v2 = 0.f, v3 = 0.f;
        #pragma unroll
        for (int nt = 0; nt < 6; ++nt) {
            int f = nt * 16 + ln15;
            float bav = ba[h * E_ + f];
            float bbv = bb[h * E_ + f];
            float wcv = Wc[h * E_ + f];
            v0 += fast_tanh(accA[nt][0] + bav) * fast_sigmoid(accG[nt][0] + bbv) * wcv;
            v1 += fast_tanh(accA[nt][1] + bav) * fast_sigmoid(accG[nt][1] + bbv) * wcv;
            v2 += fast_tanh(accA[nt][2] + bav) * fast_sigmoid(accG[nt][2] + bbv) * wcv;
            v3 += fast_tanh(accA[nt][3] + bav) * fast_sigmoid(accG[nt][3] + bbv) * wcv;
        }
        hacc[0] += v0; hacc[1] += v1; hacc[2] += v2; hacc[3] += v3;
    }

    #pragma unroll
    for (int r = 0; r < 4; ++r) {
        float v = hacc[r];
        v += __shfl_xor(v, 1, 64);
        v += __shfl_xor(v, 2, 64);
        v += __shfl_xor(v, 4, 64);
        v += __shfl_xor(v, 8, 64);
        hacc[r] = v;
    }
    if (ln15 == 0) {
        #pragma unroll
        for (int r = 0; r < 4; ++r)
            red2[mtile * 16 + q * 4 + r][hg] = hacc[r];
    }
    __syncthreads();

    if (tid < TT) {
        float bcsum = 0.0f;
        #pragma unroll
        for (int h2 = 0; h2 < H_; ++h2) bcsum += bc[h2];
        s_out[bt0 + tid] = (red2[tid][0] + red2[tid][1] + bcsum) * (1.0f / H_);
    }
}

// ---------------------------------------------------------------------------
// Kernel 2: softmax over T per batch; overwrite s with normalized weights.
// ---------------------------------------------------------------------------
__global__ __launch_bounds__(256)
void k2_softmax(float* __restrict__ s)
{
    __shared__ float red[8];
    const int b = blockIdx.x, tid = threadIdx.x, lane = tid & 63, wv = tid >> 6;
    float* sb = s + (size_t)b * T_;

    float m = -INFINITY;
    for (int t = tid; t < T_; t += 256) m = fmaxf(m, sb[t]);
    #pragma unroll
    for (int o = 32; o > 0; o >>= 1) m = fmaxf(m, __shfl_down(m, o, 64));
    if (lane == 0) red[wv] = m;
    __syncthreads();
    m = fmaxf(fmaxf(red[0], red[1]), fmaxf(red[2], red[3]));
    __syncthreads();

    float z = 0.0f;
    for (int t = tid; t < T_; t += 256) z += __expf(sb[t] - m);
    #pragma unroll
    for (int o = 32; o > 0; o >>= 1) z += __shfl_down(z, o, 64);
    if (lane == 0) red[wv] = z;
    __syncthreads();
    z = red[0] + red[1] + red[2] + red[3];
    float inv = 1.0f / z;
    for (int t = tid; t < T_; t += 256) sb[t] = __expf(sb[t] - m) * inv;
}

// ---------------------------------------------------------------------------
// Kernel 3: recompute xn per token (f32), accumulate w_t * xn, wave-private.
// ---------------------------------------------------------------------------
__global__ __launch_bounds__(256)
void k3_pool(const float* __restrict__ x,
             const float* __restrict__ gamma, const float* __restrict__ beta,
             const float* __restrict__ w,
             float* __restrict__ partial)
{
    const int tid = threadIdx.x, lane = tid & 63, wv = tid >> 6;
    const int b = blockIdx.x / NCH, ch = blockIdx.x % NCH;
    const int t0 = ch * CHT + wv * TPW3;

    float gm[12], btv[12], wl[12];
    int i0[12];
    #pragma unroll
    for (int k = 0; k < 12; ++k) {
        int j = lane + k * 64;
        gm[k] = gamma[j];
        btv[k] = beta[j];
        wl[k] = resize_w(j, &i0[k]);
    }

    float acc[12];
    #pragma unroll
    for (int k = 0; k < 12; ++k) acc[k] = 0.0f;

    for (int tt = 0; tt < TPW3; ++tt) {
        int t = t0 + tt;
        const float* xrow = x + ((size_t)b * T_ + t) * LIN;
        float xr[12];
        float sum = 0.0f, ssq = 0.0f;
        #pragma unroll
        for (int k = 0; k < 12; ++k) {
            int a = i0[k];
            int bidx = (a + 1 < LIN) ? a + 1 : LIN - 1;
            float v = xrow[a] * (1.0f - wl[k]) + xrow[bidx] * wl[k];
            xr[k] = v; sum += v; ssq += v * v;
        }
        #pragma unroll
        for (int o = 1; o < 64; o <<= 1) {
            sum += __shfl_xor(sum, o, 64);
            ssq += __shfl_xor(ssq, o, 64);
        }
        float mu = sum * (1.0f / D_);
        float rs = 1.0f / sqrtf(ssq * (1.0f / D_) - mu * mu + 1e-5f);
        float wt = w[(size_t)b * T_ + t];
        #pragma unroll
        for (int k = 0; k < 12; ++k)
            acc[k] = fmaf(wt, (xr[k] - mu) * rs * gm[k] + btv[k], acc[k]);
    }

    float* p = partial + ((size_t)blockIdx.x * 4 + wv) * D_;
    #pragma unroll
    for (int k = 0; k < 12; ++k) p[lane + k * 64] = acc[k];
}

// ---------------------------------------------------------------------------
// Kernel 4: reduce NCH*4 wave-partials per batch -> out[b, 768]
// ---------------------------------------------------------------------------
__global__ __launch_bounds__(256)
void k4_reduce(const float* __restrict__ partial, float* __restrict__ out)
{
    const int b = blockIdx.x, tid = threadIdx.x;
    const int NR = NCH * 4;
    #pragma unroll
    for (int k = 0; k < 3; ++k) {
        int j = tid + k * 256;
        const float* p = partial + (size_t)b * NR * D_ + j;
        float s = 0.0f;
        for (int c = 0; c < NR; ++c) s += p[(size_t)c * D_];
        out[b * D_ + j] = s;
    }
}

// ---------------------------------------------------------------------------
extern "C" void kernel_launch(void* const* d_in, const int* in_sizes, int n_in,
                              void* d_out, int out_size, void* d_ws, size_t ws_size,
                              hipStream_t stream)
{
    const float* x     = (const float*)d_in[0];
    // d_in[1] = lens (unused: uniform == L_IN, reference ignores it)
    const float* gamma = (const float*)d_in[2];
    const float* beta  = (const float*)d_in[3];
    const float* Wa    = (const float*)d_in[4];
    const float* ba    = (const float*)d_in[5];
    const float* Wb    = (const float*)d_in[6];
    const float* bb    = (const float*)d_in[7];
    const float* Wc    = (const float*)d_in[8];
    const float* bc    = (const float*)d_in[9];
    float* out = (float*)d_out;

    float* ws      = (float*)d_ws;
    float* s       = ws;                               // B*T floats (256 KB)
    float* partial = ws + B_ * T_;                     // B*NCH*4*D floats (6 MB)
    short* wtA     = (short*)(partial + B_ * NCH * 4 * D_);  // H*E*E bf16
    short* wtB     = wtA + H_ * E_ * E_;
    short* xnb     = wtB + H_ * E_ * E_;               // B*T*D bf16 (96 MB)

    const size_t NEED_SPLIT =
        (size_t)B_ * T_ * 4 + (size_t)B_ * NCH * 4 * D_ * 4 +
        (size_t)2 * H_ * E_ * E_ * 2 + (size_t)B_ * T_ * D_ * 2;

    hipLaunchKernelGGL(k0_wprep, dim3((H_ * E_ * E_ + 255) / 256), dim3(256), 0, stream,
                       Wa, Wb, wtA, wtB);

    if (ws_size >= NEED_SPLIT) {
        hipLaunchKernelGGL(kA_resln, dim3(NWA / 4), dim3(256), 0, stream,
                           x, gamma, beta, xnb);
        hipLaunchKernelGGL(kB_score, dim3(B_ * T_ / 128), dim3(256), 0, stream,
                           xnb, wtA, wtB, ba, bb, Wc, bc, s);
    } else {
        hipLaunchKernelGGL(k1_score, dim3(B_ * T_ / TT), dim3(256), 0, stream,
                           x, gamma, beta, wtA, wtB, ba, bb, Wc, bc, s);
    }

    hipLaunchKernelGGL(k2_softmax, dim3(B_), dim3(256), 0, stream, s);
    hipLaunchKernelGGL(k3_pool, dim3(B_ * NCH), dim3(256), 0, stream,
                       x, gamma, beta, s, partial);
    hipLaunchKernelGGL(k4_reduce, dim3(B_), dim3(256), 0, stream, partial, out);
}

// Round 6
// 303.338 us; speedup vs baseline: 1.1112x; 1.1112x over previous
//
#include <hip/hip_runtime.h>
#include <math.h>

// Problem constants (fixed by setup_inputs)
#define B_    8
#define T_    8192
#define LIN   1536
#define D_    768
#define H_    8
#define E_    96
#define NWA   4096          // total waves in kA (1024 blocks x 4 waves)
#define NCH3  128           // chunks per batch in k3
#define CHT3  (T_ / NCH3)   // 64 tokens per chunk

typedef float f32x4 __attribute__((ext_vector_type(4)));
typedef short s16x8 __attribute__((ext_vector_type(8)));
typedef short s16x4 __attribute__((ext_vector_type(4)));

static __device__ __forceinline__ float resize_w(int j, int* i0) {
    const float SCALE = (float)(1535.0 / 767.0);   // (L_IN-1)/(D-1), f32 like jnp
    float pos = (float)j * SCALE;
    int a = (int)floorf(pos);
    if (a > LIN - 1) a = LIN - 1;
    *i0 = a;
    return pos - (float)a;
}

static __device__ __forceinline__ float fast_sigmoid(float v) {
    return 1.0f / (1.0f + __expf(-v));
}
static __device__ __forceinline__ float fast_tanh(float v) {
    float t = __expf(-2.0f * v);
    return (1.0f - t) / (1.0f + t);
}
static __device__ __forceinline__ short f2bf(float f) {   // RNE f32 -> bf16 bits
    unsigned u = __float_as_uint(f);
    unsigned r = (u + 0x7FFFu + ((u >> 16) & 1u)) >> 16;
    return (short)r;
}

// ---------------------------------------------------------------------------
// Kernel 0: weight prep. Wa,Wb [h][e][f] f32 -> wtA,wtB [h][f][e] bf16.
// ---------------------------------------------------------------------------
__global__ __launch_bounds__(256)
void k0_wprep(const float* __restrict__ Wa, const float* __restrict__ Wb,
              short* __restrict__ wtA, short* __restrict__ wtB)
{
    int o = blockIdx.x * 256 + threadIdx.x;
    if (o >= H_ * E_ * E_) return;
    int e = o % E_;
    int f = (o / E_) % E_;
    int h = o / (E_ * E_);
    int in = h * E_ * E_ + e * E_ + f;
    wtA[o] = f2bf(Wa[in]);
    wtB[o] = f2bf(Wb[in]);
}

// ---------------------------------------------------------------------------
// Kernel A: resize + LayerNorm, one wave per token, grid-stride.
// COALESCED loads: lane owns features j = lane + 64k (lane stride in x is
// ~2 floats -> each load instruction spans ~512B contiguous, like k3 which
// runs at HBM rate). Head-major bf16 output layout is produced via a
// wave-private LDS bounce (scattered 2B LDS writes -> contiguous 8B reads ->
// fully-coalesced 512B global stores). Also stores per-token mu/rs for the
// linear pooling path.
// ---------------------------------------------------------------------------
__global__ __launch_bounds__(256)
void kA_resln(const float* __restrict__ x,
              const float* __restrict__ gamma, const float* __restrict__ beta,
              short* __restrict__ xnb, float* __restrict__ muv, float* __restrict__ rsv)
{
    __shared__ short tile[4][D_];   // wave-private slices, 6KB

    const int tid  = threadIdx.x;
    const int lane = tid & 63;
    const int wv   = tid >> 6;
    const int gw   = blockIdx.x * 4 + wv;   // 0..NWA-1

    float gm[12], btv[12], wl[12];
    int   i0[12];
    #pragma unroll
    for (int k = 0; k < 12; ++k) {
        int j = lane + k * 64;
        gm[k]  = gamma[j];
        btv[k] = beta[j];
        wl[k]  = resize_w(j, &i0[k]);
    }
    // head-major LDS offset for feature j = lane+64k:  (j&7)*96 + (j>>3)
    const int off0 = (lane & 7) * E_ + (lane >> 3);

    for (int t = gw; t < B_ * T_; t += NWA) {
        const float* xrow = x + (size_t)t * LIN;
        float xr[12];
        float sum = 0.0f, ssq = 0.0f;
        #pragma unroll
        for (int k = 0; k < 12; ++k) {
            int a  = i0[k];
            int b2 = (a + 1 < LIN) ? a + 1 : LIN - 1;
            float v = xrow[a] * (1.0f - wl[k]) + xrow[b2] * wl[k];
            xr[k] = v; sum += v; ssq += v * v;
        }
        #pragma unroll
        for (int o = 1; o < 64; o <<= 1) {
            sum += __shfl_xor(sum, o, 64);
            ssq += __shfl_xor(ssq, o, 64);
        }
        float mu = sum * (1.0f / D_);
        float rs = 1.0f / sqrtf(ssq * (1.0f / D_) - mu * mu + 1e-5f);
        if (lane == 0) { muv[t] = mu; rsv[t] = rs; }

        #pragma unroll
        for (int k = 0; k < 12; ++k)
            tile[wv][off0 + 8 * k] = f2bf((xr[k] - mu) * rs * gm[k] + btv[k]);

        // wave-private RAW: drain LDS writes before reading back
        asm volatile("s_waitcnt lgkmcnt(0)" ::: "memory");
        __builtin_amdgcn_sched_barrier(0);

        short* dst = xnb + (size_t)t * D_;
        #pragma unroll
        for (int i = 0; i < 3; ++i) {
            s16x4 v = *(const s16x4*)&tile[wv][i * 256 + lane * 4];
            *(s16x4*)&dst[i * 256 + lane * 4] = v;
        }
    }
}

// ---------------------------------------------------------------------------
// Kernel B: MFMA scoring from global bf16 xn. No LDS, no barrier.
// Wave = 32 tokens (2 M-tiles) x all 8 heads; block = 4 waves = 128 tokens.
// ---------------------------------------------------------------------------
__global__ __launch_bounds__(256)
void kB_score(const short* __restrict__ xnb,
              const short* __restrict__ wtA, const short* __restrict__ wtB,
              const float* __restrict__ ba, const float* __restrict__ bb,
              const float* __restrict__ Wc, const float* __restrict__ bc,
              float* __restrict__ s_out)
{
    const int tid  = threadIdx.x;
    const int lane = tid & 63;
    const int wv   = tid >> 6;
    const int ln15 = lane & 15;
    const int q    = lane >> 4;
    const int t0w  = (blockIdx.x * 4 + wv) * 32;

    float hacc[2][4];
    #pragma unroll
    for (int mt = 0; mt < 2; ++mt)
        #pragma unroll
        for (int r = 0; r < 4; ++r) hacc[mt][r] = 0.0f;

    #pragma unroll
    for (int h = 0; h < H_; ++h) {
        s16x8 afr[2][3];
        #pragma unroll
        for (int mt = 0; mt < 2; ++mt)
            #pragma unroll
            for (int kk = 0; kk < 3; ++kk)
                afr[mt][kk] = *(const s16x8*)&xnb[(size_t)(t0w + mt * 16 + ln15) * D_
                                                 + h * E_ + kk * 32 + q * 8];

        f32x4 accA[2][6], accG[2][6];
        #pragma unroll
        for (int mt = 0; mt < 2; ++mt)
            #pragma unroll
            for (int nt = 0; nt < 6; ++nt) {
                accA[mt][nt] = (f32x4){0.f, 0.f, 0.f, 0.f};
                accG[mt][nt] = (f32x4){0.f, 0.f, 0.f, 0.f};
            }

        #pragma unroll
        for (int nt = 0; nt < 6; ++nt) {
            const short* rA = wtA + h * (E_ * E_) + (nt * 16 + ln15) * E_ + q * 8;
            const short* rB = wtB + h * (E_ * E_) + (nt * 16 + ln15) * E_ + q * 8;
            #pragma unroll
            for (int kk = 0; kk < 3; ++kk) {
                s16x8 bA = *(const s16x8*)(rA + kk * 32);
                s16x8 bG = *(const s16x8*)(rB + kk * 32);
                #pragma unroll
                for (int mt = 0; mt < 2; ++mt) {
                    accA[mt][nt] = __builtin_amdgcn_mfma_f32_16x16x32_bf16(afr[mt][kk], bA, accA[mt][nt], 0, 0, 0);
                    accG[mt][nt] = __builtin_amdgcn_mfma_f32_16x16x32_bf16(afr[mt][kk], bG, accG[mt][nt], 0, 0, 0);
                }
            }
        }

        #pragma unroll
        for (int nt = 0; nt < 6; ++nt) {
            int f = nt * 16 + ln15;
            float bav = ba[h * E_ + f];
            float bbv = bb[h * E_ + f];
            float wcv = Wc[h * E_ + f];
            #pragma unroll
            for (int mt = 0; mt < 2; ++mt)
                #pragma unroll
                for (int r = 0; r < 4; ++r)
                    hacc[mt][r] += fast_tanh(accA[mt][nt][r] + bav)
                                 * fast_sigmoid(accG[mt][nt][r] + bbv) * wcv;
        }
    }

    #pragma unroll
    for (int mt = 0; mt < 2; ++mt)
        #pragma unroll
        for (int r = 0; r < 4; ++r) {
            float v = hacc[mt][r];
            v += __shfl_xor(v, 1, 64);
            v += __shfl_xor(v, 2, 64);
            v += __shfl_xor(v, 4, 64);
            v += __shfl_xor(v, 8, 64);
            hacc[mt][r] = v;
        }

    float bcsum = 0.0f;
    #pragma unroll
    for (int h2 = 0; h2 < H_; ++h2) bcsum += bc[h2];

    if (ln15 == 0) {
        #pragma unroll
        for (int mt = 0; mt < 2; ++mt)
            #pragma unroll
            for (int r = 0; r < 4; ++r)
                s_out[t0w + mt * 16 + q * 4 + r] = (hacc[mt][r] + bcsum) * (1.0f / H_);
    }
}

// ---------------------------------------------------------------------------
// Kernel 2: softmax over T per batch; overwrite s with normalized weights.
// ---------------------------------------------------------------------------
__global__ __launch_bounds__(256)
void k2_softmax(float* __restrict__ s)
{
    __shared__ float red[8];
    const int b = blockIdx.x, tid = threadIdx.x, lane = tid & 63, wv = tid >> 6;
    float* sb = s + (size_t)b * T_;

    float m = -INFINITY;
    for (int t = tid; t < T_; t += 256) m = fmaxf(m, sb[t]);
    #pragma unroll
    for (int o = 32; o > 0; o >>= 1) m = fmaxf(m, __shfl_down(m, o, 64));
    if (lane == 0) red[wv] = m;
    __syncthreads();
    m = fmaxf(fmaxf(red[0], red[1]), fmaxf(red[2], red[3]));
    __syncthreads();

    float z = 0.0f;
    for (int t = tid; t < T_; t += 256) z += __expf(sb[t] - m);
    #pragma unroll
    for (int o = 32; o > 0; o >>= 1) z += __shfl_down(z, o, 64);
    if (lane == 0) red[wv] = z;
    __syncthreads();
    z = red[0] + red[1] + red[2] + red[3];
    float inv = 1.0f / z;
    for (int t = tid; t < T_; t += 256) sb[t] = __expf(sb[t] - m) * inv;
}

// ---------------------------------------------------------------------------
// Kernel 3: linear pooling, stage 1. feats = gamma*(resize(S) - M) + beta*W
// where S[i] = sum_t c_t * x[t][i] (1536-dim, c_t = w_t*rs_t),
//       M    = sum_t c_t * mu_t,   W = sum_t w_t.
// Block = one 64-token chunk; thread owns 6 columns; fully coalesced; no sync.
// ---------------------------------------------------------------------------
__global__ __launch_bounds__(256)
void k3_pool(const float* __restrict__ x, const float* __restrict__ w,
             const float* __restrict__ rsv, const float* __restrict__ muv,
             float* __restrict__ partial, float* __restrict__ pm)
{
    const int tid = threadIdx.x;
    const int b   = blockIdx.x / NCH3, ch = blockIdx.x % NCH3;
    const int t0  = b * T_ + ch * CHT3;

    float acc[6] = {0.f, 0.f, 0.f, 0.f, 0.f, 0.f};
    float msum = 0.0f, wsum = 0.0f;

    for (int tt = 0; tt < CHT3; ++tt) {
        int t = t0 + tt;
        const float* xrow = x + (size_t)t * LIN;
        float wt = w[t];
        float c  = wt * rsv[t];
        msum = fmaf(c, muv[t], msum);
        wsum += wt;
        #pragma unroll
        for (int k = 0; k < 6; ++k)
            acc[k] = fmaf(c, xrow[tid + k * 256], acc[k]);
    }

    float* p = partial + (size_t)blockIdx.x * LIN;
    #pragma unroll
    for (int k = 0; k < 6; ++k) p[tid + k * 256] = acc[k];
    if (tid == 0) { pm[blockIdx.x * 2] = msum; pm[blockIdx.x * 2 + 1] = wsum; }
}

// ---------------------------------------------------------------------------
// Kernel 4: reduce chunk partials -> S[1536]; resize + affine -> out[b,768].
// ---------------------------------------------------------------------------
__global__ __launch_bounds__(256)
void k4_reduce(const float* __restrict__ partial, const float* __restrict__ pm,
               const float* __restrict__ gamma, const float* __restrict__ beta,
               float* __restrict__ out)
{
    __shared__ float S[LIN];
    const int b = blockIdx.x, tid = threadIdx.x;

    float a[6] = {0.f, 0.f, 0.f, 0.f, 0.f, 0.f};
    for (int ch = 0; ch < NCH3; ++ch) {
        const float* p = partial + ((size_t)b * NCH3 + ch) * LIN;
        #pragma unroll
        for (int k = 0; k < 6; ++k) a[k] += p[tid + k * 256];
    }
    #pragma unroll
    for (int k = 0; k < 6; ++k) S[tid + k * 256] = a[k];

    float M = 0.0f, W = 0.0f;
    for (int ch = 0; ch < NCH3; ++ch) {
        M += pm[(b * NCH3 + ch) * 2];
        W += pm[(b * NCH3 + ch) * 2 + 1];
    }
    __syncthreads();

    #pragma unroll
    for (int k = 0; k < 3; ++k) {
        int j = tid + k * 256;
        int a0;
        float wl = resize_w(j, &a0);
        int a1 = (a0 + 1 < LIN) ? a0 + 1 : LIN - 1;
        float Sp = S[a0] * (1.0f - wl) + S[a1] * wl;
        out[b * D_ + j] = gamma[j] * (Sp - M) + beta[j] * W;
    }
}

// ---------------------------------------------------------------------------
extern "C" void kernel_launch(void* const* d_in, const int* in_sizes, int n_in,
                              void* d_out, int out_size, void* d_ws, size_t ws_size,
                              hipStream_t stream)
{
    const float* x     = (const float*)d_in[0];
    // d_in[1] = lens (unused: uniform == L_IN, reference ignores it)
    const float* gamma = (const float*)d_in[2];
    const float* beta  = (const float*)d_in[3];
    const float* Wa    = (const float*)d_in[4];
    const float* ba    = (const float*)d_in[5];
    const float* Wb    = (const float*)d_in[6];
    const float* bb    = (const float*)d_in[7];
    const float* Wc    = (const float*)d_in[8];
    const float* bc    = (const float*)d_in[9];
    float* out = (float*)d_out;

    float* ws      = (float*)d_ws;
    float* s       = ws;                                   // B*T f32 (256 KB)
    float* muv     = s + B_ * T_;                          // B*T f32
    float* rsv     = muv + B_ * T_;                        // B*T f32
    float* partial = rsv + B_ * T_;                        // B*NCH3*1536 f32 (6.3 MB)
    float* pm      = partial + (size_t)B_ * NCH3 * LIN;    // B*NCH3*2 f32
    short* wtA     = (short*)(pm + B_ * NCH3 * 2);         // H*E*E bf16
    short* wtB     = wtA + H_ * E_ * E_;
    short* xnb     = wtB + H_ * E_ * E_;                   // B*T*D bf16 (96 MB)

    hipLaunchKernelGGL(k0_wprep, dim3((H_ * E_ * E_ + 255) / 256), dim3(256), 0, stream,
                       Wa, Wb, wtA, wtB);
    hipLaunchKernelGGL(kA_resln, dim3(NWA / 4), dim3(256), 0, stream,
                       x, gamma, beta, xnb, muv, rsv);
    hipLaunchKernelGGL(kB_score, dim3(B_ * T_ / 128), dim3(256), 0, stream,
                       xnb, wtA, wtB, ba, bb, Wc, bc, s);
    hipLaunchKernelGGL(k2_softmax, dim3(B_), dim3(256), 0, stream, s);
    hipLaunchKernelGGL(k3_pool, dim3(B_ * NCH3), dim3(256), 0, stream,
                       x, s, rsv, muv, partial, pm);
    hipLaunchKernelGGL(k4_reduce, dim3(B_), dim3(256), 0, stream,
                       partial, pm, gamma, beta, out);
}